// Round 1
// baseline (939.072 us; speedup 1.0000x reference)
//
#include <hip/hip_runtime.h>
#include <hip/hip_bf16.h>

namespace {

constexpr int M = 8192;
constexpr int N = 4096;
constexpr int K = 4096;
constexpr int BM = 128, BN = 128, BK = 32;
constexpr int LDA = 40;  // bf16 elems/row: 32 data + 8 pad = 80 B (16B-aligned, 2-way banks = free)
constexpr int LDB = 40;
constexpr float CLIP = 100.0f;
constexpr float THRESH = 0.5f;

typedef __bf16 bf16x8 __attribute__((ext_vector_type(8)));
typedef __bf16 bf16x4 __attribute__((ext_vector_type(4)));
typedef float f32x4 __attribute__((ext_vector_type(4)));

__global__ __launch_bounds__(256) void ternary_gemm_kernel(
    const float* __restrict__ x, const float* __restrict__ W,
    const float* __restrict__ scale, const float* __restrict__ bias,
    float* __restrict__ out)
{
  __shared__ __bf16 sA[BM * LDA];
  __shared__ __bf16 sB[BN * LDB];

  const int tid  = threadIdx.x;
  const int lane = tid & 63;
  const int wave = tid >> 6;
  const int wm   = (wave >> 1) * 64;   // wave sub-tile origin (m)
  const int wn   = (wave & 1) * 64;    // wave sub-tile origin (n)
  const int l15  = lane & 15;
  const int quad = lane >> 4;

  const int bm = blockIdx.y * BM;
  const int bn = blockIdx.x * BN;

  // A staging: 1024 float4 per tile, 4 per thread; 8 float4 per 32-col row
  const int a_row = tid >> 3;
  const int a_c4  = tid & 7;
  // B staging: 4x4 micro-tile per thread (4 k-rows x 4 n-cols), register transpose
  const int b_kg = tid >> 5;   // 0..7 -> k rows b_kg*4 .. +3
  const int b_ng = tid & 31;   // 0..31 -> n cols b_ng*4 .. +3

  f32x4 acc[4][4] = {};

  for (int k0 = 0; k0 < K; k0 += BK) {
    // ---- stage A: x (fp32) -> bf16 LDS, row-major k-contiguous ----
#pragma unroll
    for (int i = 0; i < 4; ++i) {
      const int row = a_row + i * 32;
      const float4 v = *reinterpret_cast<const float4*>(
          x + (size_t)(bm + row) * K + k0 + a_c4 * 4);
      bf16x4 c;
      c[0] = (__bf16)v.x; c[1] = (__bf16)v.y; c[2] = (__bf16)v.z; c[3] = (__bf16)v.w;
      *reinterpret_cast<bf16x4*>(&sA[row * LDA + a_c4 * 4]) = c;
    }

    // ---- stage B: ternarize W (fp32) -> bf16, transpose to n-major/k-contiguous ----
    {
      __bf16 t[4][4];
#pragma unroll
      for (int j = 0; j < 4; ++j) {
        const float4 v = *reinterpret_cast<const float4*>(
            W + (size_t)(k0 + b_kg * 4 + j) * N + bn + b_ng * 4);
        const float a0[4] = {v.x, v.y, v.z, v.w};
#pragma unroll
        for (int c = 0; c < 4; ++c) {
          const float w = a0[c];
          const float q = (w > THRESH) ? 1.0f : ((w < -THRESH) ? -1.0f : 0.0f);
          t[j][c] = (__bf16)q;
        }
      }
#pragma unroll
      for (int c = 0; c < 4; ++c) {
        bf16x4 col;
        col[0] = t[0][c]; col[1] = t[1][c]; col[2] = t[2][c]; col[3] = t[3][c];
        *reinterpret_cast<bf16x4*>(&sB[(b_ng * 4 + c) * LDB + b_kg * 4]) = col;
      }
    }
    __syncthreads();

    // ---- MFMA compute: 4x4 fragments of 16x16x32 per wave ----
    bf16x8 af[4], bfr[4];
#pragma unroll
    for (int i = 0; i < 4; ++i)
      af[i] = *reinterpret_cast<const bf16x8*>(
          &sA[(wm + i * 16 + l15) * LDA + quad * 8]);
#pragma unroll
    for (int j = 0; j < 4; ++j)
      bfr[j] = *reinterpret_cast<const bf16x8*>(
          &sB[(wn + j * 16 + l15) * LDB + quad * 8]);
#pragma unroll
    for (int i = 0; i < 4; ++i) {
#pragma unroll
      for (int j = 0; j < 4; ++j) {
        acc[i][j] = __builtin_amdgcn_mfma_f32_16x16x32_bf16(
            af[i], bfr[j], acc[i][j], 0, 0, 0);
      }
    }
    __syncthreads();
  }

  // ---- epilogue: scale, bias, clip; C/D layout col=lane&15, row=quad*4+reg ----
#pragma unroll
  for (int j = 0; j < 4; ++j) {
    const int n = bn + wn + j * 16 + l15;
    const float s = scale[n];
    const float b = bias[n];
#pragma unroll
    for (int i = 0; i < 4; ++i) {
#pragma unroll
      for (int r = 0; r < 4; ++r) {
        const int m = bm + wm + i * 16 + quad * 4 + r;
        float v = acc[i][j][r] * s + b;
        v = fminf(fmaxf(v, -CLIP), CLIP);
        out[(size_t)m * N + n] = v;
      }
    }
  }
}

}  // namespace

extern "C" void kernel_launch(void* const* d_in, const int* in_sizes, int n_in,
                              void* d_out, int out_size, void* d_ws, size_t ws_size,
                              hipStream_t stream) {
  const float* x     = (const float*)d_in[0];
  const float* W     = (const float*)d_in[1];
  const float* scale = (const float*)d_in[2];
  const float* bias  = (const float*)d_in[3];
  float* out = (float*)d_out;

  dim3 grid(N / BN, M / BM);
  ternary_gemm_kernel<<<grid, dim3(256), 0, stream>>>(x, W, scale, bias, out);
}

// Round 2
// 624.009 us; speedup vs baseline: 1.5049x; 1.5049x over previous
//
#include <hip/hip_runtime.h>
#include <hip/hip_bf16.h>
#include <stdint.h>

namespace {

constexpr int M = 8192;
constexpr int N = 4096;
constexpr int K = 4096;
constexpr float CLIP = 100.0f;
constexpr float THRESH = 0.5f;

typedef __bf16 bf16x8 __attribute__((ext_vector_type(8)));
typedef __bf16 bf16x4 __attribute__((ext_vector_type(4)));
typedef float f32x4 __attribute__((ext_vector_type(4)));

__device__ __forceinline__ void load16_to_lds(const void* gptr, void* lptr) {
  __builtin_amdgcn_global_load_lds(
      (const __attribute__((address_space(1))) uint32_t*)gptr,
      (__attribute__((address_space(3))) uint32_t*)lptr,
      16, 0, 0);
}

__device__ __forceinline__ __bf16 tern(float w) {
  return (__bf16)((w > THRESH) ? 1.0f : ((w < -THRESH) ? -1.0f : 0.0f));
}

// ---- prep 1: x fp32 -> bf16, same row-major layout ----
__global__ __launch_bounds__(256) void prep_x_kernel(
    const float* __restrict__ x, __bf16* __restrict__ xb) {
  const int total = M * K / 4;
  const int stride = gridDim.x * blockDim.x;
  for (int i = blockIdx.x * blockDim.x + threadIdx.x; i < total; i += stride) {
    const float4 v = reinterpret_cast<const float4*>(x)[i];
    bf16x4 c;
    c[0] = (__bf16)v.x; c[1] = (__bf16)v.y; c[2] = (__bf16)v.z; c[3] = (__bf16)v.w;
    reinterpret_cast<bf16x4*>(xb)[i] = c;
  }
}

// ---- prep 2: W [K][N] fp32 -> ternarize -> transpose -> Wt [N][K] bf16 ----
__global__ __launch_bounds__(256) void prep_w_kernel(
    const float* __restrict__ W, __bf16* __restrict__ Wt) {
  __shared__ __bf16 sT[64][68];  // 136 B rows: 8B-aligned bf16x4 stores
  const int t = threadIdx.x;
  const int k0 = blockIdx.y * 64;
  const int n0 = blockIdx.x * 64;

#pragma unroll
  for (int i = 0; i < 4; ++i) {
    const int k = i * 16 + (t >> 4);
    const int n4 = (t & 15);
    const float4 v = *reinterpret_cast<const float4*>(
        W + (size_t)(k0 + k) * N + n0 + n4 * 4);
    bf16x4 c;
    c[0] = tern(v.x); c[1] = tern(v.y); c[2] = tern(v.z); c[3] = tern(v.w);
    *reinterpret_cast<bf16x4*>(&sT[k][n4 * 4]) = c;
  }
  __syncthreads();
#pragma unroll
  for (int i = 0; i < 4; ++i) {
    const int n = i * 16 + (t >> 4);
    const int k4 = (t & 15);
    bf16x4 c;
#pragma unroll
    for (int cc = 0; cc < 4; ++cc) c[cc] = sT[k4 * 4 + cc][n];
    *reinterpret_cast<bf16x4*>(Wt + (size_t)(n0 + n) * K + k0 + k4 * 4) = c;
  }
}

// ---- main: bf16 B^T GEMM, m97 structure (global_load_lds width=16) ----
__global__ __launch_bounds__(256) void gemm_bt_kernel(
    const __bf16* __restrict__ A, const __bf16* __restrict__ Bt,
    const float* __restrict__ scale, const float* __restrict__ bias,
    float* __restrict__ out) {
  // Unpadded: 32 bf16 = 64 B rows, required by global_load_lds lane ordering.
  __shared__ __bf16 sA[128 * 32];
  __shared__ __bf16 sB[128 * 32];

  const int tid  = threadIdx.x;
  const int lane = tid & 63;
  const int wave = tid >> 6;
  const int wm   = (wave >> 1) * 64;
  const int wn   = (wave & 1) * 64;
  const int l15  = lane & 15;
  const int quad = lane >> 4;

  const int bm = blockIdx.y * 128;
  const int bn = blockIdx.x * 128;

  // staging: each wave issues 2 chunks for A, 2 for B; chunk = 16 rows x 64 B = 1024 B
  const int ar = lane >> 2;        // row within 16-row chunk
  const int ac = (lane & 3) * 8;   // k offset (bf16 elems)

  f32x4 acc[4][4] = {};

  for (int k0 = 0; k0 < K; k0 += 32) {
#pragma unroll
    for (int q = 0; q < 2; ++q) {
      const int chunk = wave * 2 + q;
      const int row = chunk * 16 + ar;
      load16_to_lds(A  + (size_t)(bm + row) * K + k0 + ac, &sA[chunk * 512]);
      load16_to_lds(Bt + (size_t)(bn + row) * K + k0 + ac, &sB[chunk * 512]);
    }
    __syncthreads();

    bf16x8 af[4], bfr[4];
#pragma unroll
    for (int i = 0; i < 4; ++i)
      af[i] = *reinterpret_cast<const bf16x8*>(&sA[(wm + i * 16 + l15) * 32 + quad * 8]);
#pragma unroll
    for (int j = 0; j < 4; ++j)
      bfr[j] = *reinterpret_cast<const bf16x8*>(&sB[(wn + j * 16 + l15) * 32 + quad * 8]);
#pragma unroll
    for (int i = 0; i < 4; ++i)
#pragma unroll
      for (int j = 0; j < 4; ++j)
        acc[i][j] = __builtin_amdgcn_mfma_f32_16x16x32_bf16(af[i], bfr[j], acc[i][j], 0, 0, 0);
    __syncthreads();
  }

  // epilogue: scale, bias, clip; C/D layout col=lane&15, row=quad*4+reg
#pragma unroll
  for (int j = 0; j < 4; ++j) {
    const int n = bn + wn + j * 16 + l15;
    const float s = scale[n];
    const float b = bias[n];
#pragma unroll
    for (int i = 0; i < 4; ++i) {
#pragma unroll
      for (int r = 0; r < 4; ++r) {
        const int m = bm + wm + i * 16 + quad * 4 + r;
        float v = acc[i][j][r] * s + b;
        v = fminf(fmaxf(v, -CLIP), CLIP);
        out[(size_t)m * N + n] = v;
      }
    }
  }
}

// ================= round-1 fallback (ws too small) =================
constexpr int LDA = 40;
constexpr int LDB = 40;

__global__ __launch_bounds__(256) void ternary_gemm_fallback(
    const float* __restrict__ x, const float* __restrict__ W,
    const float* __restrict__ scale, const float* __restrict__ bias,
    float* __restrict__ out) {
  __shared__ __bf16 sA[128 * LDA];
  __shared__ __bf16 sB[128 * LDB];

  const int tid  = threadIdx.x;
  const int lane = tid & 63;
  const int wave = tid >> 6;
  const int wm   = (wave >> 1) * 64;
  const int wn   = (wave & 1) * 64;
  const int l15  = lane & 15;
  const int quad = lane >> 4;
  const int bm = blockIdx.y * 128;
  const int bn = blockIdx.x * 128;
  const int a_row = tid >> 3;
  const int a_c4  = tid & 7;
  const int b_kg = tid >> 5;
  const int b_ng = tid & 31;

  f32x4 acc[4][4] = {};
  for (int k0 = 0; k0 < K; k0 += 32) {
#pragma unroll
    for (int i = 0; i < 4; ++i) {
      const int row = a_row + i * 32;
      const float4 v = *reinterpret_cast<const float4*>(
          x + (size_t)(bm + row) * K + k0 + a_c4 * 4);
      bf16x4 c;
      c[0] = (__bf16)v.x; c[1] = (__bf16)v.y; c[2] = (__bf16)v.z; c[3] = (__bf16)v.w;
      *reinterpret_cast<bf16x4*>(&sA[row * LDA + a_c4 * 4]) = c;
    }
    {
      __bf16 t[4][4];
#pragma unroll
      for (int j = 0; j < 4; ++j) {
        const float4 v = *reinterpret_cast<const float4*>(
            W + (size_t)(k0 + b_kg * 4 + j) * N + bn + b_ng * 4);
        t[j][0] = tern(v.x); t[j][1] = tern(v.y); t[j][2] = tern(v.z); t[j][3] = tern(v.w);
      }
#pragma unroll
      for (int c = 0; c < 4; ++c) {
        bf16x4 col;
        col[0] = t[0][c]; col[1] = t[1][c]; col[2] = t[2][c]; col[3] = t[3][c];
        *reinterpret_cast<bf16x4*>(&sB[(b_ng * 4 + c) * LDB + b_kg * 4]) = col;
      }
    }
    __syncthreads();
    bf16x8 af[4], bfr[4];
#pragma unroll
    for (int i = 0; i < 4; ++i)
      af[i] = *reinterpret_cast<const bf16x8*>(&sA[(wm + i * 16 + l15) * LDA + quad * 8]);
#pragma unroll
    for (int j = 0; j < 4; ++j)
      bfr[j] = *reinterpret_cast<const bf16x8*>(&sB[(wn + j * 16 + l15) * LDB + quad * 8]);
#pragma unroll
    for (int i = 0; i < 4; ++i)
#pragma unroll
      for (int j = 0; j < 4; ++j)
        acc[i][j] = __builtin_amdgcn_mfma_f32_16x16x32_bf16(af[i], bfr[j], acc[i][j], 0, 0, 0);
    __syncthreads();
  }
#pragma unroll
  for (int j = 0; j < 4; ++j) {
    const int n = bn + wn + j * 16 + l15;
    const float s = scale[n];
    const float b = bias[n];
#pragma unroll
    for (int i = 0; i < 4; ++i)
#pragma unroll
      for (int r = 0; r < 4; ++r) {
        const int m = bm + wm + i * 16 + quad * 4 + r;
        float v = acc[i][j][r] * s + b;
        v = fminf(fmaxf(v, -CLIP), CLIP);
        out[(size_t)m * N + n] = v;
      }
  }
}

}  // namespace

extern "C" void kernel_launch(void* const* d_in, const int* in_sizes, int n_in,
                              void* d_out, int out_size, void* d_ws, size_t ws_size,
                              hipStream_t stream) {
  const float* x     = (const float*)d_in[0];
  const float* W     = (const float*)d_in[1];
  const float* scale = (const float*)d_in[2];
  const float* bias  = (const float*)d_in[3];
  float* out = (float*)d_out;

  const size_t xb_bytes = (size_t)M * K * sizeof(__bf16);   // 67.1 MB
  const size_t wt_bytes = (size_t)N * K * sizeof(__bf16);   // 33.5 MB

  if (ws_size >= xb_bytes + wt_bytes) {
    __bf16* xb = (__bf16*)d_ws;
    __bf16* wt = (__bf16*)((char*)d_ws + xb_bytes);
    prep_x_kernel<<<2048, 256, 0, stream>>>(x, xb);
    prep_w_kernel<<<dim3(N / 64, K / 64), 256, 0, stream>>>(W, wt);
    gemm_bt_kernel<<<dim3(N / 128, M / 128), 256, 0, stream>>>(xb, wt, scale, bias, out);
  } else {
    ternary_gemm_fallback<<<dim3(N / 128, M / 128), 256, 0, stream>>>(x, W, scale, bias, out);
  }
}